// Round 5
// baseline (73.100 us; speedup 1.0000x reference)
//
#include <hip/hip_runtime.h>

#define B_ 64
#define L_ 512
#define H_ 512
#define CENTER 255

typedef float  f32x4  __attribute__((ext_vector_type(4)));
typedef _Float16 f16x8 __attribute__((ext_vector_type(8)));
typedef unsigned short u16x4 __attribute__((ext_vector_type(4)));
typedef unsigned short USH;

// ws layout (floats):
//   scores   [0,      32768)
//   dec_feat [32768,  65536)
//   cov_feat [65536,  98304)
//   Bpk     [360448, 491520)   ushort[512][512]: fp16(attn_w) bits (row-major n,k)

__device__ __forceinline__ float fast_tanh(float x) {
    float e = __expf(2.0f * x);
    return 1.0f - 2.0f * __builtin_amdgcn_rcpf(e + 1.0f);
}

// ================= pre: cov-direct (0..511) + conv_b (512..639) + dec (640..895) ========
// v2: role A drops the 133 KB coverage LDS stage (coverage is 128 KB, L2-resident).
// LDS 134 KB -> 4.3 KB => 4 blocks/CU instead of 1 => all 896 blocks co-resident,
// all scattered cvg_w line-gathers in flight at once.
// Wave w handles j in [w*64, w*64+64): wl reads are wave-uniform (LDS broadcast,
// conflict-free); lane l = batch b reads coverage as float4 from L2.
__launch_bounds__(512)
__global__ void pre_kernel(const float* __restrict__ cvg_w, const float* __restrict__ cvg_b,
                           const float* __restrict__ coverage,
                           const float* __restrict__ aw, USH* __restrict__ bh16,
                           const float* __restrict__ hidden, const float* __restrict__ dec_w,
                           const float* __restrict__ dec_b,
                           float* __restrict__ dec_feat, float* __restrict__ cov_feat) {
    __shared__ float pool[1088];       // role A: wl[512] + part[8][72]; role C: sbuf+pr
    const int bid = blockIdx.x, t = threadIdx.x;
    if (bid < 512) {
        float* wl   = pool;                        // [512]
        float* part = pool + 512;                  // [8][72] (pad 72: consecutive anyway)
        const int i = bid;
        wl[t] = cvg_w[((size_t)(i * L_ + t)) * H_ + CENTER];   // 1 scattered line/thread
        __syncthreads();
        const int w = t >> 6, l = t & 63;          // wave w = col-seg, lane l = batch b
        const float4* cov4 = (const float4*)&coverage[(size_t)l * L_ + w * 64];
        float sum = 0.f;
        #pragma unroll
        for (int jj4 = 0; jj4 < 16; ++jj4) {
            float4 c = cov4[jj4];
            const float* wseg = &wl[w * 64 + jj4 * 4];   // wave-uniform -> broadcast
            sum += c.x * wseg[0] + c.y * wseg[1] + c.z * wseg[2] + c.w * wseg[3];
        }
        part[w * 72 + l] = sum;
        __syncthreads();
        if (t < 64) {
            float s = 0.f;
            #pragma unroll
            for (int g = 0; g < 8; ++g) s += part[g * 72 + t];
            cov_feat[t * L_ + i] = s + cvg_b[i];
        }
    } else if (bid < 640) {
        int i = (bid - 512) * 512 + t;             // float4 per thread
        float4 x = *(const float4*)&aw[(size_t)i * 4];
        float xs[4] = {x.x, x.y, x.z, x.w};
        u16x4 h;
        #pragma unroll
        for (int j = 0; j < 4; ++j)
            h[j] = __builtin_bit_cast(USH, (_Float16)xs[j]);
        *(u16x4*)&bh16[(size_t)i * 4] = h;
    } else {
        float* sbuf = pool;                        // [512]
        float* pr   = pool + 512;                  // [512] (overlaps part; different role)
        const int blk = bid - 640, b = blk >> 2, qq = blk & 3;
        const int ol = t & 127, part_ = t >> 7;
        sbuf[t] = hidden[b * H_ + t];
        __syncthreads();
        const float* row  = dec_w + (size_t)(qq * 128 + ol) * H_ + part_ * 128;
        const float* hseg = sbuf + part_ * 128;
        float d0 = 0.f, d1 = 0.f, d2 = 0.f, d3 = 0.f;
        #pragma unroll
        for (int k = 0; k < 128; k += 16) {
            float4 w0 = *(const float4*)&row[k];
            float4 w1 = *(const float4*)&row[k + 4];
            float4 w2 = *(const float4*)&row[k + 8];
            float4 w3 = *(const float4*)&row[k + 12];
            d0 += w0.x * hseg[k]      + w0.y * hseg[k + 1]  + w0.z * hseg[k + 2]  + w0.w * hseg[k + 3];
            d1 += w1.x * hseg[k + 4]  + w1.y * hseg[k + 5]  + w1.z * hseg[k + 6]  + w1.w * hseg[k + 7];
            d2 += w2.x * hseg[k + 8]  + w2.y * hseg[k + 9]  + w2.z * hseg[k + 10] + w2.w * hseg[k + 11];
            d3 += w3.x * hseg[k + 12] + w3.y * hseg[k + 13] + w3.z * hseg[k + 14] + w3.w * hseg[k + 15];
        }
        pr[t] = d0 + d1 + d2 + d3;
        __syncthreads();
        if (t < 128)
            dec_feat[b * H_ + qq * 128 + t] = pr[t] + pr[t + 128] + pr[t + 256] + pr[t + 384]
                                              + dec_b[qq * 128 + t];
    }
}

// ================= fused MFMA GEMM (fp16) + tanh + dot(v) -> scores =====================
// (byte-identical to the 67.7 us baseline: BM=128, grid 256, 16 waves 2Mx8N, B triple-
//  buffered depth-2, A reg-prefetch depth-2 + LDS dbuf, ONE barrier/step, counted vmcnt(3).)
#define BM 128

#define STAGE_B(BUF, KS1)                                                                  \
    {                                                                                      \
        _Pragma("unroll")                                                                  \
        for (int it = 0; it < 2; ++it)                                                     \
            __builtin_amdgcn_global_load_lds(                                              \
                (const __attribute__((address_space(1))) void*)(bh16 + goffB[it] + (KS1) * 32), \
                (__attribute__((address_space(3))) void*)&Bsh[BUF][(wv * 2 + it) * 512],   \
                16, 0, 0);                                                                 \
    }

#define CVTWRITEA(BUF, A4)                                                                 \
    {                                                                                      \
        float axs[4] = {A4.x, A4.y, A4.z, A4.w};                                           \
        u16x4 hh;                                                                          \
        _Pragma("unroll")                                                                  \
        for (int j = 0; j < 4; ++j)                                                        \
            hh[j] = __builtin_bit_cast(USH, (_Float16)axs[j]);                             \
        *(u16x4*)&Ash[BUF][awoff] = hh;                                                    \
    }

__launch_bounds__(1024, 4)
__global__ void fused_score_mfma(const float* __restrict__ enc,
                                 const USH* __restrict__ bh16,
                                 const float* __restrict__ attn_b,
                                 const float* __restrict__ dec_feat,
                                 const float* __restrict__ cov_feat,
                                 const float* __restrict__ v,
                                 float* __restrict__ scores) {
    __shared__ USH Bsh[3][16384];      // [buf][512n x 32k swizzled fp16] = 96 KB
    __shared__ USH Ash[2][4096];       // [buf][128r x 32k swizzled fp16] = 16 KB

    const int t  = threadIdx.x;
    const int wv = t >> 6, ln = t & 63;
    const int wr = wv >> 3, wc = wv & 7;     // 2M x 8N, wave tile 64 x 64
    const int q  = ln >> 4, cl = ln & 15;
    const int m0 = blockIdx.x * BM;
    const int b  = blockIdx.x >> 2;          // 4 row-tiles per batch row

    int goffB[2];
    #pragma unroll
    for (int it = 0; it < 2; ++it) {
        int c   = wv * 2 + it;
        int srl = ln >> 3;
        int u   = (ln & 7) ^ (srl & 7);
        int n   = c * 16 + srl * 2 + (u >> 2);
        goffB[it] = n * 512 + (u & 3) * 8;
    }
    const int sA   = (((cl & 1) * 4 + q) ^ ((cl >> 1) & 7)) * 8;
    const int aoff = wr * 2048 + (cl >> 1) * 64 + sA;
    const int boff = wc * 2048 + (cl >> 1) * 64 + sA;

    const int arow = t >> 3, akoct = t & 7;
    const int asw  = ((arow & 1) * 4 + (akoct >> 1)) ^ ((arow >> 1) & 7);
    const int awoff = (arow >> 1) * 64 + asw * 8 + (akoct & 1) * 4;
    const float* agsrc = enc + (size_t)(m0 + arow) * H_ + akoct * 4;

    f32x4 acc[4][4];
    #pragma unroll
    for (int mf = 0; mf < 4; ++mf)
        #pragma unroll
        for (int nf = 0; nf < 4; ++nf) acc[mf][nf] = (f32x4){0.f, 0.f, 0.f, 0.f};

    float4 aP = *(const float4*)(agsrc + 32);
    float4 c0 = *(const float4*)agsrc;
    __builtin_amdgcn_sched_barrier(0);
    STAGE_B(0, 0);
    STAGE_B(1, 1);
    __builtin_amdgcn_sched_barrier(0);
    CVTWRITEA(0, c0);
    asm volatile("s_waitcnt lgkmcnt(0)" ::: "memory");
    asm volatile("s_waitcnt vmcnt(2)" ::: "memory");
    __builtin_amdgcn_sched_barrier(0);
    __builtin_amdgcn_s_barrier();

    #pragma unroll
    for (int ks = 0; ks < 16; ++ks) {
        const int curB = ks % 3;
        const int curA = ks & 1, nxtA = curA ^ 1;
        float4 aN;
        if (ks < 14) {
            STAGE_B((ks + 2) % 3, ks + 2);
            aN = *(const float4*)(agsrc + (ks + 2) * 32);
            __builtin_amdgcn_sched_barrier(0);
        }

        f16x8 ah[4];
        #pragma unroll
        for (int mf = 0; mf < 4; ++mf)
            ah[mf] = *(const f16x8*)&Ash[curA][aoff + mf * 512];
        __builtin_amdgcn_s_setprio(1);
        #pragma unroll
        for (int nf = 0; nf < 4; ++nf) {
            f16x8 bh = *(const f16x8*)&Bsh[curB][boff + nf * 512];
            #pragma unroll
            for (int mf = 0; mf < 4; ++mf)
                acc[mf][nf] = __builtin_amdgcn_mfma_f32_16x16x32_f16(ah[mf], bh, acc[mf][nf], 0, 0, 0);
        }
        __builtin_amdgcn_s_setprio(0);

        if (ks < 15) {
            CVTWRITEA(nxtA, aP);
            aP = aN;
            asm volatile("s_waitcnt lgkmcnt(0)" ::: "memory");
            if (ks < 14)
                asm volatile("s_waitcnt vmcnt(3)" ::: "memory");
            else
                asm volatile("s_waitcnt vmcnt(0)" ::: "memory");
            __builtin_amdgcn_sched_barrier(0);
            __builtin_amdgcn_s_barrier();
        }
    }
    __syncthreads();

    float (*scred)[BM] = (float (*)[BM])Ash;
    float addv[4], vvv[4];
    #pragma unroll
    for (int nf = 0; nf < 4; ++nf) {
        int n = wc * 64 + nf * 16 + cl;
        addv[nf] = attn_b[n] + dec_feat[b * H_ + n];
        vvv[nf]  = v[b * H_ + n];
    }
    #pragma unroll
    for (int mf = 0; mf < 4; ++mf) {
        #pragma unroll
        for (int reg = 0; reg < 4; ++reg) {
            int row = wr * 64 + mf * 16 + q * 4 + reg;
            float cf = cov_feat[m0 + row];
            float s = 0.f;
            #pragma unroll
            for (int nf = 0; nf < 4; ++nf)
                s += fast_tanh(acc[mf][nf][reg] + addv[nf] + cf) * vvv[nf];
            s += __shfl_xor(s, 1, 64);
            s += __shfl_xor(s, 2, 64);
            s += __shfl_xor(s, 4, 64);
            s += __shfl_xor(s, 8, 64);
            if (cl == 0) scred[wc][row] = s;
        }
    }
    __syncthreads();
    if (t < BM) {
        float s = 0.f;
        #pragma unroll
        for (int g = 0; g < 8; ++g) s += scred[g][t];
        scores[m0 + t] = s;
    }
}

// ================= smctx: masked softmax + outputs + context ============================
// (byte-identical to R3: 1024 threads, float4 enc loads, LDS [32][32] float4 reduce.)
__launch_bounds__(1024)
__global__ void smctx_kernel(const float* __restrict__ scores, const int* __restrict__ mask,
                             const float* __restrict__ coverage, const float* __restrict__ enc,
                             float* __restrict__ out) {
    __shared__ float w[512];
    __shared__ float red[16];
    __shared__ float red2[16];
    __shared__ float4 cred4[32][32];   // 16 KB
    const int bid = blockIdx.x, b = bid >> 2, hc = bid & 3, t = threadIdx.x;
    const int wv = t >> 6, ln = t & 63;

    float sv = 0.f; bool mk = false;
    if (t < 512) {
        mk = (mask[b * L_ + t] == 1);
        sv = scores[b * L_ + t];
    }
    float val = (t < 512 && mk) ? sv : -INFINITY;

    float r = val;
    #pragma unroll
    for (int d = 1; d <= 32; d <<= 1) r = fmaxf(r, __shfl_xor(r, d, 64));
    if (ln == 0) red[wv] = r;
    __syncthreads();
    float gmax = red[0];
    #pragma unroll
    for (int i = 1; i < 16; ++i) gmax = fmaxf(gmax, red[i]);

    float p = (t < 512 && mk) ? __expf(sv - gmax) : 0.f;
    float qq = p;
    #pragma unroll
    for (int d = 1; d <= 32; d <<= 1) qq += __shfl_xor(qq, d, 64);
    if (ln == 0) red2[wv] = qq;
    __syncthreads();
    float tot = 0.f;
    #pragma unroll
    for (int i = 0; i < 16; ++i) tot += red2[i];

    float wt = p / tot;
    if (t < 512) {
        w[t] = wt;
        if (hc == 0) {
            out[B_ * H_ + b * L_ + t] = wt;                                   // attn_weights
            out[B_ * H_ + B_ * L_ + b * L_ + t] = coverage[b * L_ + t] + wt;  // new_coverage
        }
    }
    __syncthreads();

    const int c4 = t & 31, rg = t >> 5;    // 32 row-groups x 32 float4 columns
    const float4* ebase = (const float4*)enc
                          + ((size_t)(b * L_ + rg)) * 128 + hc * 32 + c4;
    float4 a4 = {0.f, 0.f, 0.f, 0.f};
    #pragma unroll
    for (int k = 0; k < 16; ++k) {         // rows rg, rg+32, ..., rg+480
        float wl_ = w[rg + 32 * k];
        float4 e = ebase[(size_t)(32 * k) * 128];
        a4.x += wl_ * e.x; a4.y += wl_ * e.y; a4.z += wl_ * e.z; a4.w += wl_ * e.w;
    }
    cred4[rg][c4] = a4;
    __syncthreads();
    if (t < 32) {
        float4 s = {0.f, 0.f, 0.f, 0.f};
        #pragma unroll
        for (int g = 0; g < 32; ++g) {
            float4 c = cred4[g][t];
            s.x += c.x; s.y += c.y; s.z += c.z; s.w += c.w;
        }
        *(float4*)&out[b * H_ + hc * 128 + t * 4] = s;
    }
}

extern "C" void kernel_launch(void* const* d_in, const int* in_sizes, int n_in,
                              void* d_out, int out_size, void* d_ws, size_t ws_size,
                              hipStream_t stream) {
    const float* enc      = (const float*)d_in[0];
    const int*   mask     = (const int*)d_in[1];
    const float* hidden   = (const float*)d_in[2];
    const float* coverage = (const float*)d_in[3];
    const float* attn_w   = (const float*)d_in[4];
    const float* attn_b   = (const float*)d_in[5];
    const float* dec_w    = (const float*)d_in[6];
    const float* dec_b    = (const float*)d_in[7];
    const float* cvg_w    = (const float*)d_in[8];
    const float* cvg_b    = (const float*)d_in[9];
    const float* v        = (const float*)d_in[10];
    float* out = (float*)d_out;
    float* ws  = (float*)d_ws;
    float* scores   = ws;
    float* dec_feat = ws + 32768;
    float* cov_feat = ws + 65536;
    USH* bpk = (USH*)(ws + 360448);

    hipLaunchKernelGGL(pre_kernel,       dim3(896),  dim3(512),  0, stream,
                       cvg_w, cvg_b, coverage, attn_w, bpk, hidden, dec_w, dec_b,
                       dec_feat, cov_feat);
    hipLaunchKernelGGL(fused_score_mfma, dim3(256),  dim3(1024), 0, stream,
                       enc, bpk, attn_b, dec_feat, cov_feat, v, scores);
    hipLaunchKernelGGL(smctx_kernel,     dim3(256),  dim3(1024), 0, stream,
                       scores, mask, coverage, enc, out);
}

// Round 6
// 70.089 us; speedup vs baseline: 1.0430x; 1.0430x over previous
//
#include <hip/hip_runtime.h>

#define B_ 64
#define L_ 512
#define H_ 512
#define CENTER 255

typedef float  f32x4  __attribute__((ext_vector_type(4)));
typedef _Float16 f16x8 __attribute__((ext_vector_type(8)));
typedef unsigned short u16x4 __attribute__((ext_vector_type(4)));
typedef unsigned short USH;

// ws layout (floats):
//   scores   [0,      32768)
//   dec_feat [32768,  65536)
//   cov_feat [65536,  98304)
//   Bpk     [360448, 491520)   ushort[512][512]: fp16(attn_w) bits (row-major n,k)

__device__ __forceinline__ float fast_tanh(float x) {
    float e = __expf(2.0f * x);
    return 1.0f - 2.0f * __builtin_amdgcn_rcpf(e + 1.0f);
}

// ================= preA: cov-direct (512 blocks, 134 KB LDS) ============================
// R3's role-A verbatim: gather w_eff[i,:] -> LDS; stage FULL coverage (128KB) transposed
// in LDS (pad 65); 8 thr/b x 64 j MACs; shfl-reduce. Coalesced loads throughout.
__launch_bounds__(512)
__global__ void preA_kernel(const float* __restrict__ cvg_w, const float* __restrict__ cvg_b,
                            const float* __restrict__ coverage,
                            float* __restrict__ cov_feat) {
    __shared__ float pool[34304];      // wl[512] + cs[512][65]
    const int t = threadIdx.x;
    float* wl = pool;                          // [512]
    float* cs = pool + 512;                    // [j][c] = [512][65]
    const int i = blockIdx.x;
    wl[t] = cvg_w[((size_t)(i * L_ + t)) * H_ + CENTER];   // 1 scattered line/thread
    #pragma unroll 8
    for (int c = 0; c < 64; ++c)
        cs[t * 65 + c] = coverage[c * L_ + t];             // coalesced; write 2/bank
    __syncthreads();
    const int b = t >> 3, jg = t & 7;
    float sum = 0.f;
    #pragma unroll 8
    for (int jj = 0; jj < 64; ++jj) {
        int j = jg * 64 + ((jj + jg * 8) & 63);            // rotation: read 2/bank
        sum += cs[j * 65 + b] * wl[j];
    }
    sum += __shfl_xor(sum, 1, 64);
    sum += __shfl_xor(sum, 2, 64);
    sum += __shfl_xor(sum, 4, 64);
    if (jg == 0) cov_feat[b * L_ + i] = sum + cvg_b[i];
}

// ================= preBC: attn_w pack (0..127) + dec GEMV (128..383), 4 KB LDS ==========
// Split from preA so these blocks run 4/CU (wave-limited) instead of inheriting the
// 134 KB allocation -> all 384 co-resident in one dispatch round.
__launch_bounds__(512)
__global__ void preBC_kernel(const float* __restrict__ aw, USH* __restrict__ bh16,
                             const float* __restrict__ hidden, const float* __restrict__ dec_w,
                             const float* __restrict__ dec_b,
                             float* __restrict__ dec_feat) {
    __shared__ float pool[1024];       // sbuf[512] + pr[512]
    const int bid = blockIdx.x, t = threadIdx.x;
    if (bid < 128) {
        int i = bid * 512 + t;                     // float4 per thread
        float4 x = *(const float4*)&aw[(size_t)i * 4];
        float xs[4] = {x.x, x.y, x.z, x.w};
        u16x4 h;
        #pragma unroll
        for (int j = 0; j < 4; ++j)
            h[j] = __builtin_bit_cast(USH, (_Float16)xs[j]);
        *(u16x4*)&bh16[(size_t)i * 4] = h;
    } else {
        float* sbuf = pool;                        // [512]
        float* pr   = pool + 512;                  // [512]
        const int blk = bid - 128, b = blk >> 2, qq = blk & 3;
        const int ol = t & 127, part = t >> 7;
        sbuf[t] = hidden[b * H_ + t];
        __syncthreads();
        const float* row  = dec_w + (size_t)(qq * 128 + ol) * H_ + part * 128;
        const float* hseg = sbuf + part * 128;
        float d0 = 0.f, d1 = 0.f, d2 = 0.f, d3 = 0.f;
        #pragma unroll
        for (int k = 0; k < 128; k += 16) {
            float4 w0 = *(const float4*)&row[k];
            float4 w1 = *(const float4*)&row[k + 4];
            float4 w2 = *(const float4*)&row[k + 8];
            float4 w3 = *(const float4*)&row[k + 12];
            d0 += w0.x * hseg[k]      + w0.y * hseg[k + 1]  + w0.z * hseg[k + 2]  + w0.w * hseg[k + 3];
            d1 += w1.x * hseg[k + 4]  + w1.y * hseg[k + 5]  + w1.z * hseg[k + 6]  + w1.w * hseg[k + 7];
            d2 += w2.x * hseg[k + 8]  + w2.y * hseg[k + 9]  + w2.z * hseg[k + 10] + w2.w * hseg[k + 11];
            d3 += w3.x * hseg[k + 12] + w3.y * hseg[k + 13] + w3.z * hseg[k + 14] + w3.w * hseg[k + 15];
        }
        pr[t] = d0 + d1 + d2 + d3;
        __syncthreads();
        if (t < 128)
            dec_feat[b * H_ + qq * 128 + t] = pr[t] + pr[t + 128] + pr[t + 256] + pr[t + 384]
                                              + dec_b[qq * 128 + t];
    }
}

// ================= fused MFMA GEMM (fp16) + tanh + dot(v) -> scores =====================
// (byte-identical to the 67.7 us baseline: BM=128, grid 256, 16 waves 2Mx8N, B triple-
//  buffered depth-2, A reg-prefetch depth-2 + LDS dbuf, ONE barrier/step, counted vmcnt(3).)
#define BM 128

#define STAGE_B(BUF, KS1)                                                                  \
    {                                                                                      \
        _Pragma("unroll")                                                                  \
        for (int it = 0; it < 2; ++it)                                                     \
            __builtin_amdgcn_global_load_lds(                                              \
                (const __attribute__((address_space(1))) void*)(bh16 + goffB[it] + (KS1) * 32), \
                (__attribute__((address_space(3))) void*)&Bsh[BUF][(wv * 2 + it) * 512],   \
                16, 0, 0);                                                                 \
    }

#define CVTWRITEA(BUF, A4)                                                                 \
    {                                                                                      \
        float axs[4] = {A4.x, A4.y, A4.z, A4.w};                                           \
        u16x4 hh;                                                                          \
        _Pragma("unroll")                                                                  \
        for (int j = 0; j < 4; ++j)                                                        \
            hh[j] = __builtin_bit_cast(USH, (_Float16)axs[j]);                             \
        *(u16x4*)&Ash[BUF][awoff] = hh;                                                    \
    }

__launch_bounds__(1024, 4)
__global__ void fused_score_mfma(const float* __restrict__ enc,
                                 const USH* __restrict__ bh16,
                                 const float* __restrict__ attn_b,
                                 const float* __restrict__ dec_feat,
                                 const float* __restrict__ cov_feat,
                                 const float* __restrict__ v,
                                 float* __restrict__ scores) {
    __shared__ USH Bsh[3][16384];      // [buf][512n x 32k swizzled fp16] = 96 KB
    __shared__ USH Ash[2][4096];       // [buf][128r x 32k swizzled fp16] = 16 KB

    const int t  = threadIdx.x;
    const int wv = t >> 6, ln = t & 63;
    const int wr = wv >> 3, wc = wv & 7;     // 2M x 8N, wave tile 64 x 64
    const int q  = ln >> 4, cl = ln & 15;
    const int m0 = blockIdx.x * BM;
    const int b  = blockIdx.x >> 2;          // 4 row-tiles per batch row

    int goffB[2];
    #pragma unroll
    for (int it = 0; it < 2; ++it) {
        int c   = wv * 2 + it;
        int srl = ln >> 3;
        int u   = (ln & 7) ^ (srl & 7);
        int n   = c * 16 + srl * 2 + (u >> 2);
        goffB[it] = n * 512 + (u & 3) * 8;
    }
    const int sA   = (((cl & 1) * 4 + q) ^ ((cl >> 1) & 7)) * 8;
    const int aoff = wr * 2048 + (cl >> 1) * 64 + sA;
    const int boff = wc * 2048 + (cl >> 1) * 64 + sA;

    const int arow = t >> 3, akoct = t & 7;
    const int asw  = ((arow & 1) * 4 + (akoct >> 1)) ^ ((arow >> 1) & 7);
    const int awoff = (arow >> 1) * 64 + asw * 8 + (akoct & 1) * 4;
    const float* agsrc = enc + (size_t)(m0 + arow) * H_ + akoct * 4;

    f32x4 acc[4][4];
    #pragma unroll
    for (int mf = 0; mf < 4; ++mf)
        #pragma unroll
        for (int nf = 0; nf < 4; ++nf) acc[mf][nf] = (f32x4){0.f, 0.f, 0.f, 0.f};

    float4 aP = *(const float4*)(agsrc + 32);
    float4 c0 = *(const float4*)agsrc;
    __builtin_amdgcn_sched_barrier(0);
    STAGE_B(0, 0);
    STAGE_B(1, 1);
    __builtin_amdgcn_sched_barrier(0);
    CVTWRITEA(0, c0);
    asm volatile("s_waitcnt lgkmcnt(0)" ::: "memory");
    asm volatile("s_waitcnt vmcnt(2)" ::: "memory");
    __builtin_amdgcn_sched_barrier(0);
    __builtin_amdgcn_s_barrier();

    #pragma unroll
    for (int ks = 0; ks < 16; ++ks) {
        const int curB = ks % 3;
        const int curA = ks & 1, nxtA = curA ^ 1;
        float4 aN;
        if (ks < 14) {
            STAGE_B((ks + 2) % 3, ks + 2);
            aN = *(const float4*)(agsrc + (ks + 2) * 32);
            __builtin_amdgcn_sched_barrier(0);
        }

        f16x8 ah[4];
        #pragma unroll
        for (int mf = 0; mf < 4; ++mf)
            ah[mf] = *(const f16x8*)&Ash[curA][aoff + mf * 512];
        __builtin_amdgcn_s_setprio(1);
        #pragma unroll
        for (int nf = 0; nf < 4; ++nf) {
            f16x8 bh = *(const f16x8*)&Bsh[curB][boff + nf * 512];
            #pragma unroll
            for (int mf = 0; mf < 4; ++mf)
                acc[mf][nf] = __builtin_amdgcn_mfma_f32_16x16x32_f16(ah[mf], bh, acc[mf][nf], 0, 0, 0);
        }
        __builtin_amdgcn_s_setprio(0);

        if (ks < 15) {
            CVTWRITEA(nxtA, aP);
            aP = aN;
            asm volatile("s_waitcnt lgkmcnt(0)" ::: "memory");
            if (ks < 14)
                asm volatile("s_waitcnt vmcnt(3)" ::: "memory");
            else
                asm volatile("s_waitcnt vmcnt(0)" ::: "memory");
            __builtin_amdgcn_sched_barrier(0);
            __builtin_amdgcn_s_barrier();
        }
    }
    __syncthreads();

    float (*scred)[BM] = (float (*)[BM])Ash;
    float addv[4], vvv[4];
    #pragma unroll
    for (int nf = 0; nf < 4; ++nf) {
        int n = wc * 64 + nf * 16 + cl;
        addv[nf] = attn_b[n] + dec_feat[b * H_ + n];
        vvv[nf]  = v[b * H_ + n];
    }
    #pragma unroll
    for (int mf = 0; mf < 4; ++mf) {
        #pragma unroll
        for (int reg = 0; reg < 4; ++reg) {
            int row = wr * 64 + mf * 16 + q * 4 + reg;
            float cf = cov_feat[m0 + row];
            float s = 0.f;
            #pragma unroll
            for (int nf = 0; nf < 4; ++nf)
                s += fast_tanh(acc[mf][nf][reg] + addv[nf] + cf) * vvv[nf];
            s += __shfl_xor(s, 1, 64);
            s += __shfl_xor(s, 2, 64);
            s += __shfl_xor(s, 4, 64);
            s += __shfl_xor(s, 8, 64);
            if (cl == 0) scred[wc][row] = s;
        }
    }
    __syncthreads();
    if (t < BM) {
        float s = 0.f;
        #pragma unroll
        for (int g = 0; g < 8; ++g) s += scred[g][t];
        scores[m0 + t] = s;
    }
}

// ================= smctx: masked softmax + outputs + context ============================
// (byte-identical to R3: 1024 threads, float4 enc loads, LDS [32][32] float4 reduce.)
__launch_bounds__(1024)
__global__ void smctx_kernel(const float* __restrict__ scores, const int* __restrict__ mask,
                             const float* __restrict__ coverage, const float* __restrict__ enc,
                             float* __restrict__ out) {
    __shared__ float w[512];
    __shared__ float red[16];
    __shared__ float red2[16];
    __shared__ float4 cred4[32][32];   // 16 KB
    const int bid = blockIdx.x, b = bid >> 2, hc = bid & 3, t = threadIdx.x;
    const int wv = t >> 6, ln = t & 63;

    float sv = 0.f; bool mk = false;
    if (t < 512) {
        mk = (mask[b * L_ + t] == 1);
        sv = scores[b * L_ + t];
    }
    float val = (t < 512 && mk) ? sv : -INFINITY;

    float r = val;
    #pragma unroll
    for (int d = 1; d <= 32; d <<= 1) r = fmaxf(r, __shfl_xor(r, d, 64));
    if (ln == 0) red[wv] = r;
    __syncthreads();
    float gmax = red[0];
    #pragma unroll
    for (int i = 1; i < 16; ++i) gmax = fmaxf(gmax, red[i]);

    float p = (t < 512 && mk) ? __expf(sv - gmax) : 0.f;
    float qq = p;
    #pragma unroll
    for (int d = 1; d <= 32; d <<= 1) qq += __shfl_xor(qq, d, 64);
    if (ln == 0) red2[wv] = qq;
    __syncthreads();
    float tot = 0.f;
    #pragma unroll
    for (int i = 0; i < 16; ++i) tot += red2[i];

    float wt = p / tot;
    if (t < 512) {
        w[t] = wt;
        if (hc == 0) {
            out[B_ * H_ + b * L_ + t] = wt;                                   // attn_weights
            out[B_ * H_ + B_ * L_ + b * L_ + t] = coverage[b * L_ + t] + wt;  // new_coverage
        }
    }
    __syncthreads();

    const int c4 = t & 31, rg = t >> 5;    // 32 row-groups x 32 float4 columns
    const float4* ebase = (const float4*)enc
                          + ((size_t)(b * L_ + rg)) * 128 + hc * 32 + c4;
    float4 a4 = {0.f, 0.f, 0.f, 0.f};
    #pragma unroll
    for (int k = 0; k < 16; ++k) {         // rows rg, rg+32, ..., rg+480
        float wl_ = w[rg + 32 * k];
        float4 e = ebase[(size_t)(32 * k) * 128];
        a4.x += wl_ * e.x; a4.y += wl_ * e.y; a4.z += wl_ * e.z; a4.w += wl_ * e.w;
    }
    cred4[rg][c4] = a4;
    __syncthreads();
    if (t < 32) {
        float4 s = {0.f, 0.f, 0.f, 0.f};
        #pragma unroll
        for (int g = 0; g < 32; ++g) {
            float4 c = cred4[g][t];
            s.x += c.x; s.y += c.y; s.z += c.z; s.w += c.w;
        }
        *(float4*)&out[b * H_ + hc * 128 + t * 4] = s;
    }
}

extern "C" void kernel_launch(void* const* d_in, const int* in_sizes, int n_in,
                              void* d_out, int out_size, void* d_ws, size_t ws_size,
                              hipStream_t stream) {
    const float* enc      = (const float*)d_in[0];
    const int*   mask     = (const int*)d_in[1];
    const float* hidden   = (const float*)d_in[2];
    const float* coverage = (const float*)d_in[3];
    const float* attn_w   = (const float*)d_in[4];
    const float* attn_b   = (const float*)d_in[5];
    const float* dec_w    = (const float*)d_in[6];
    const float* dec_b    = (const float*)d_in[7];
    const float* cvg_w    = (const float*)d_in[8];
    const float* cvg_b    = (const float*)d_in[9];
    const float* v        = (const float*)d_in[10];
    float* out = (float*)d_out;
    float* ws  = (float*)d_ws;
    float* scores   = ws;
    float* dec_feat = ws + 32768;
    float* cov_feat = ws + 65536;
    USH* bpk = (USH*)(ws + 360448);

    hipLaunchKernelGGL(preBC_kernel,     dim3(384),  dim3(512),  0, stream,
                       attn_w, bpk, hidden, dec_w, dec_b, dec_feat);
    hipLaunchKernelGGL(preA_kernel,      dim3(512),  dim3(512),  0, stream,
                       cvg_w, cvg_b, coverage, cov_feat);
    hipLaunchKernelGGL(fused_score_mfma, dim3(256),  dim3(1024), 0, stream,
                       enc, bpk, attn_b, dec_feat, cov_feat, v, scores);
    hipLaunchKernelGGL(smctx_kernel,     dim3(256),  dim3(1024), 0, stream,
                       scores, mask, coverage, enc, out);
}

// Round 7
// 67.434 us; speedup vs baseline: 1.0840x; 1.0394x over previous
//
#include <hip/hip_runtime.h>

#define B_ 64
#define L_ 512
#define H_ 512
#define CENTER 255

typedef float  f32x4  __attribute__((ext_vector_type(4)));
typedef _Float16 f16x8 __attribute__((ext_vector_type(8)));
typedef unsigned short u16x4 __attribute__((ext_vector_type(4)));
typedef unsigned short u16x8 __attribute__((ext_vector_type(8)));
typedef unsigned short USH;

// ws layout (floats):
//   (free)    [0,      32768)
//   dec_feat [32768,  65536)
//   cov_feat [65536,  98304)
//   spart    [98304,  163840)  float[2][32768]: per-N-half partial scores
//   Bpk     [360448, 491520)   ushort[512][512]: fp16(attn_w) bits (row-major n,k)

__device__ __forceinline__ float fast_tanh(float x) {
    float e = __expf(2.0f * x);
    return 1.0f - 2.0f * __builtin_amdgcn_rcpf(e + 1.0f);
}

// ================= pre: cov-direct (0..511) + conv_b (512..639) + dec (640..895) ========
// (R3's merged pre, verbatim — best measured config.)
__launch_bounds__(512)
__global__ void pre_kernel(const float* __restrict__ cvg_w, const float* __restrict__ cvg_b,
                           const float* __restrict__ coverage,
                           const float* __restrict__ aw, USH* __restrict__ bh16,
                           const float* __restrict__ hidden, const float* __restrict__ dec_w,
                           const float* __restrict__ dec_b,
                           float* __restrict__ dec_feat, float* __restrict__ cov_feat) {
    __shared__ float pool[34304];      // role A: wl[512] + cs[512][65]; role C: sbuf+pr
    const int bid = blockIdx.x, t = threadIdx.x;
    if (bid < 512) {
        float* wl = pool;                          // [512]
        float* cs = pool + 512;                    // [j][c] = [512][65]
        const int i = bid;
        wl[t] = cvg_w[((size_t)(i * L_ + t)) * H_ + CENTER];   // 1 scattered line/thread
        #pragma unroll 8
        for (int c = 0; c < 64; ++c)
            cs[t * 65 + c] = coverage[c * L_ + t];             // coalesced; write 2/bank
        __syncthreads();
        const int b = t >> 3, jg = t & 7;
        float sum = 0.f;
        #pragma unroll 8
        for (int jj = 0; jj < 64; ++jj) {
            int j = jg * 64 + ((jj + jg * 8) & 63);            // rotation: read 2/bank
            sum += cs[j * 65 + b] * wl[j];
        }
        sum += __shfl_xor(sum, 1, 64);
        sum += __shfl_xor(sum, 2, 64);
        sum += __shfl_xor(sum, 4, 64);
        if (jg == 0) cov_feat[b * L_ + i] = sum + cvg_b[i];
    } else if (bid < 640) {
        int i = (bid - 512) * 512 + t;             // float4 per thread
        float4 x = *(const float4*)&aw[(size_t)i * 4];
        float xs[4] = {x.x, x.y, x.z, x.w};
        u16x4 h;
        #pragma unroll
        for (int j = 0; j < 4; ++j)
            h[j] = __builtin_bit_cast(USH, (_Float16)xs[j]);
        *(u16x4*)&bh16[(size_t)i * 4] = h;
    } else {
        float* sbuf = pool;                        // [512]
        float* pr   = pool + 512;                  // [512]
        const int blk = bid - 640, b = blk >> 2, qq = blk & 3;
        const int ol = t & 127, part = t >> 7;
        sbuf[t] = hidden[b * H_ + t];
        __syncthreads();
        const float* row  = dec_w + (size_t)(qq * 128 + ol) * H_ + part * 128;
        const float* hseg = sbuf + part * 128;
        float d0 = 0.f, d1 = 0.f, d2 = 0.f, d3 = 0.f;
        #pragma unroll
        for (int k = 0; k < 128; k += 16) {
            float4 w0 = *(const float4*)&row[k];
            float4 w1 = *(const float4*)&row[k + 4];
            float4 w2 = *(const float4*)&row[k + 8];
            float4 w3 = *(const float4*)&row[k + 12];
            d0 += w0.x * hseg[k]      + w0.y * hseg[k + 1]  + w0.z * hseg[k + 2]  + w0.w * hseg[k + 3];
            d1 += w1.x * hseg[k + 4]  + w1.y * hseg[k + 5]  + w1.z * hseg[k + 6]  + w1.w * hseg[k + 7];
            d2 += w2.x * hseg[k + 8]  + w2.y * hseg[k + 9]  + w2.z * hseg[k + 10] + w2.w * hseg[k + 11];
            d3 += w3.x * hseg[k + 12] + w3.y * hseg[k + 13] + w3.z * hseg[k + 14] + w3.w * hseg[k + 15];
        }
        pr[t] = d0 + d1 + d2 + d3;
        __syncthreads();
        if (t < 128)
            dec_feat[b * H_ + qq * 128 + t] = pr[t] + pr[t + 128] + pr[t + 256] + pr[t + 384]
                                              + dec_b[qq * 128 + t];
    }
}

// ================= fused MFMA GEMM (fp16) + tanh + dot(v) -> partial scores =============
// v3: N split in halves (BN=256) for 2 blocks/CU. 512 thr = 8 waves (2M x 4N, wave tile
// 64x64). LDS 64 KB (Bsh 3x16KB + Ash 2x8KB). Same swizzles/schedule as the 67.7 us
// baseline; vmcnt recounted (4 VMEM/step). Each half writes partial scores (the score
// is an exact sum over n); smctx adds the two halves. No cross-block sync.
#define BM 128

#define STAGE_B(BUF, KS1)                                                                  \
    {                                                                                      \
        _Pragma("unroll")                                                                  \
        for (int it = 0; it < 2; ++it)                                                     \
            __builtin_amdgcn_global_load_lds(                                              \
                (const __attribute__((address_space(1))) void*)(bh16 + goffB[it] + (KS1) * 32), \
                (__attribute__((address_space(3))) void*)&Bsh[BUF][(wv * 2 + it) * 512],   \
                16, 0, 0);                                                                 \
    }

#define CVTWRITEA2(BUF, A4a, A4b)                                                          \
    {                                                                                      \
        float axs[8] = {A4a.x, A4a.y, A4a.z, A4a.w, A4b.x, A4b.y, A4b.z, A4b.w};           \
        u16x8 hh;                                                                          \
        _Pragma("unroll")                                                                  \
        for (int j = 0; j < 8; ++j)                                                        \
            hh[j] = __builtin_bit_cast(USH, (_Float16)axs[j]);                             \
        *(u16x8*)&Ash[BUF][awoff] = hh;                                                    \
    }

__launch_bounds__(512, 4)
__global__ void fused_score_mfma(const float* __restrict__ enc,
                                 const USH* __restrict__ bh16,
                                 const float* __restrict__ attn_b,
                                 const float* __restrict__ dec_feat,
                                 const float* __restrict__ cov_feat,
                                 const float* __restrict__ v,
                                 float* __restrict__ spart) {
    __shared__ USH Bsh[3][8192];       // [buf][256n x 32k swizzled fp16] = 48 KB
    __shared__ USH Ash[2][4096];       // [buf][128r x 32k swizzled fp16] = 16 KB

    const int t  = threadIdx.x;
    const int wv = t >> 6, ln = t & 63;
    const int wr = wv >> 2, wc = wv & 3;     // 2M x 4N, wave tile 64 x 64
    const int q  = ln >> 4, cl = ln & 15;
    const int mt = blockIdx.x, half = blockIdx.y;
    const int m0 = mt * BM;
    const int b  = mt >> 2;                  // 4 row-tiles per batch row
    const int n0 = half * 256;

    int goffB[2];
    #pragma unroll
    for (int it = 0; it < 2; ++it) {
        int c   = wv * 2 + it;               // 16 chunks cover 256 n
        int srl = ln >> 3;
        int u   = (ln & 7) ^ (srl & 7);
        int n   = n0 + c * 16 + srl * 2 + (u >> 2);
        goffB[it] = n * 512 + (u & 3) * 8;
    }
    const int sA   = (((cl & 1) * 4 + q) ^ ((cl >> 1) & 7)) * 8;
    const int aoff = wr * 2048 + (cl >> 1) * 64 + sA;
    const int boff = wc * 2048 + (cl >> 1) * 64 + sA;

    const int arow = t >> 2, ak4 = t & 3;    // 512 thr: 8 floats (2 float4) per thread
    const int asw  = ((arow & 1) * 4 + ak4) ^ ((arow >> 1) & 7);
    const int awoff = (arow >> 1) * 64 + asw * 8;
    const float* agsrc = enc + (size_t)(m0 + arow) * H_ + ak4 * 8;

    f32x4 acc[4][4];
    #pragma unroll
    for (int mf = 0; mf < 4; ++mf)
        #pragma unroll
        for (int nf = 0; nf < 4; ++nf) acc[mf][nf] = (f32x4){0.f, 0.f, 0.f, 0.f};

    float4 aPa = *(const float4*)(agsrc + 32);
    float4 aPb = *(const float4*)(agsrc + 36);
    float4 c0a = *(const float4*)agsrc;
    float4 c0b = *(const float4*)(agsrc + 4);
    __builtin_amdgcn_sched_barrier(0);
    STAGE_B(0, 0);
    STAGE_B(1, 1);
    __builtin_amdgcn_sched_barrier(0);
    CVTWRITEA2(0, c0a, c0b);
    asm volatile("s_waitcnt lgkmcnt(0)" ::: "memory");
    asm volatile("s_waitcnt vmcnt(2)" ::: "memory");
    __builtin_amdgcn_sched_barrier(0);
    __builtin_amdgcn_s_barrier();

    #pragma unroll
    for (int ks = 0; ks < 16; ++ks) {
        const int curB = ks % 3;
        const int curA = ks & 1, nxtA = curA ^ 1;
        float4 aNa, aNb;
        if (ks < 14) {
            STAGE_B((ks + 2) % 3, ks + 2);
            aNa = *(const float4*)(agsrc + (ks + 2) * 32);
            aNb = *(const float4*)(agsrc + (ks + 2) * 32 + 4);
            __builtin_amdgcn_sched_barrier(0);
        }

        f16x8 ah[4];
        #pragma unroll
        for (int mf = 0; mf < 4; ++mf)
            ah[mf] = *(const f16x8*)&Ash[curA][aoff + mf * 512];
        __builtin_amdgcn_s_setprio(1);
        #pragma unroll
        for (int nf = 0; nf < 4; ++nf) {
            f16x8 bh = *(const f16x8*)&Bsh[curB][boff + nf * 512];
            #pragma unroll
            for (int mf = 0; mf < 4; ++mf)
                acc[mf][nf] = __builtin_amdgcn_mfma_f32_16x16x32_f16(ah[mf], bh, acc[mf][nf], 0, 0, 0);
        }
        __builtin_amdgcn_s_setprio(0);

        if (ks < 15) {
            CVTWRITEA2(nxtA, aPa, aPb);
            aPa = aNa; aPb = aNb;
            asm volatile("s_waitcnt lgkmcnt(0)" ::: "memory");
            if (ks < 14)
                asm volatile("s_waitcnt vmcnt(4)" ::: "memory");
            else
                asm volatile("s_waitcnt vmcnt(0)" ::: "memory");
            __builtin_amdgcn_sched_barrier(0);
            __builtin_amdgcn_s_barrier();
        }
    }
    __syncthreads();

    float (*scred)[BM] = (float (*)[BM])Ash;
    float addv[4], vvv[4];
    #pragma unroll
    for (int nf = 0; nf < 4; ++nf) {
        int n = n0 + wc * 64 + nf * 16 + cl;
        addv[nf] = attn_b[n] + dec_feat[b * H_ + n];
        vvv[nf]  = v[b * H_ + n];
    }
    #pragma unroll
    for (int mf = 0; mf < 4; ++mf) {
        #pragma unroll
        for (int reg = 0; reg < 4; ++reg) {
            int row = wr * 64 + mf * 16 + q * 4 + reg;
            float cf = cov_feat[m0 + row];
            float s = 0.f;
            #pragma unroll
            for (int nf = 0; nf < 4; ++nf)
                s += fast_tanh(acc[mf][nf][reg] + addv[nf] + cf) * vvv[nf];
            s += __shfl_xor(s, 1, 64);
            s += __shfl_xor(s, 2, 64);
            s += __shfl_xor(s, 4, 64);
            s += __shfl_xor(s, 8, 64);
            if (cl == 0) scred[wc][row] = s;
        }
    }
    __syncthreads();
    if (t < BM) {
        float s = 0.f;
        #pragma unroll
        for (int g = 0; g < 4; ++g) s += scred[g][t];
        spart[half * (B_ * L_) + m0 + t] = s;
    }
}

// ================= smctx: masked softmax + outputs + context ============================
// (R3 verbatim except scores = spart[0] + spart[1].)
__launch_bounds__(1024)
__global__ void smctx_kernel(const float* __restrict__ spart, const int* __restrict__ mask,
                             const float* __restrict__ coverage, const float* __restrict__ enc,
                             float* __restrict__ out) {
    __shared__ float w[512];
    __shared__ float red[16];
    __shared__ float red2[16];
    __shared__ float4 cred4[32][32];   // 16 KB
    const int bid = blockIdx.x, b = bid >> 2, hc = bid & 3, t = threadIdx.x;
    const int wv = t >> 6, ln = t & 63;

    float sv = 0.f; bool mk = false;
    if (t < 512) {
        mk = (mask[b * L_ + t] == 1);
        sv = spart[b * L_ + t] + spart[B_ * L_ + b * L_ + t];
    }
    float val = (t < 512 && mk) ? sv : -INFINITY;

    float r = val;
    #pragma unroll
    for (int d = 1; d <= 32; d <<= 1) r = fmaxf(r, __shfl_xor(r, d, 64));
    if (ln == 0) red[wv] = r;
    __syncthreads();
    float gmax = red[0];
    #pragma unroll
    for (int i = 1; i < 16; ++i) gmax = fmaxf(gmax, red[i]);

    float p = (t < 512 && mk) ? __expf(sv - gmax) : 0.f;
    float qq = p;
    #pragma unroll
    for (int d = 1; d <= 32; d <<= 1) qq += __shfl_xor(qq, d, 64);
    if (ln == 0) red2[wv] = qq;
    __syncthreads();
    float tot = 0.f;
    #pragma unroll
    for (int i = 0; i < 16; ++i) tot += red2[i];

    float wt = p / tot;
    if (t < 512) {
        w[t] = wt;
        if (hc == 0) {
            out[B_ * H_ + b * L_ + t] = wt;                                   // attn_weights
            out[B_ * H_ + B_ * L_ + b * L_ + t] = coverage[b * L_ + t] + wt;  // new_coverage
        }
    }
    __syncthreads();

    const int c4 = t & 31, rg = t >> 5;    // 32 row-groups x 32 float4 columns
    const float4* ebase = (const float4*)enc
                          + ((size_t)(b * L_ + rg)) * 128 + hc * 32 + c4;
    float4 a4 = {0.f, 0.f, 0.f, 0.f};
    #pragma unroll
    for (int k = 0; k < 16; ++k) {         // rows rg, rg+32, ..., rg+480
        float wl_ = w[rg + 32 * k];
        float4 e = ebase[(size_t)(32 * k) * 128];
        a4.x += wl_ * e.x; a4.y += wl_ * e.y; a4.z += wl_ * e.z; a4.w += wl_ * e.w;
    }
    cred4[rg][c4] = a4;
    __syncthreads();
    if (t < 32) {
        float4 s = {0.f, 0.f, 0.f, 0.f};
        #pragma unroll
        for (int g = 0; g < 32; ++g) {
            float4 c = cred4[g][t];
            s.x += c.x; s.y += c.y; s.z += c.z; s.w += c.w;
        }
        *(float4*)&out[b * H_ + hc * 128 + t * 4] = s;
    }
}

extern "C" void kernel_launch(void* const* d_in, const int* in_sizes, int n_in,
                              void* d_out, int out_size, void* d_ws, size_t ws_size,
                              hipStream_t stream) {
    const float* enc      = (const float*)d_in[0];
    const int*   mask     = (const int*)d_in[1];
    const float* hidden   = (const float*)d_in[2];
    const float* coverage = (const float*)d_in[3];
    const float* attn_w   = (const float*)d_in[4];
    const float* attn_b   = (const float*)d_in[5];
    const float* dec_w    = (const float*)d_in[6];
    const float* dec_b    = (const float*)d_in[7];
    const float* cvg_w    = (const float*)d_in[8];
    const float* cvg_b    = (const float*)d_in[9];
    const float* v        = (const float*)d_in[10];
    float* out = (float*)d_out;
    float* ws  = (float*)d_ws;
    float* dec_feat = ws + 32768;
    float* cov_feat = ws + 65536;
    float* spart    = ws + 98304;
    USH* bpk = (USH*)(ws + 360448);

    hipLaunchKernelGGL(pre_kernel,       dim3(896),     dim3(512),  0, stream,
                       cvg_w, cvg_b, coverage, attn_w, bpk, hidden, dec_w, dec_b,
                       dec_feat, cov_feat);
    hipLaunchKernelGGL(fused_score_mfma, dim3(256, 2),  dim3(512),  0, stream,
                       enc, bpk, attn_b, dec_feat, cov_feat, v, spart);
    hipLaunchKernelGGL(smctx_kernel,     dim3(256),     dim3(1024), 0, stream,
                       spart, mask, coverage, enc, out);
}

// Round 8
// 64.702 us; speedup vs baseline: 1.1298x; 1.0422x over previous
//
#include <hip/hip_runtime.h>

#define B_ 64
#define L_ 512
#define H_ 512
#define CENTER 255

typedef float  f32x4  __attribute__((ext_vector_type(4)));
typedef _Float16 f16x8 __attribute__((ext_vector_type(8)));
typedef unsigned short u16x4 __attribute__((ext_vector_type(4)));
typedef unsigned short u16x8 __attribute__((ext_vector_type(8)));
typedef unsigned short USH;

// ws layout (floats):
//   (free)    [0,      32768)
//   dec_feat [32768,  65536)
//   cov_feat [65536,  98304)
//   spart    [98304,  163840)  float[2][32768]: per-N-half partial scores
//   Bpk     [360448, 491520)   ushort[512][512]: fp16(attn_w) bits (row-major n,k)

__device__ __forceinline__ float fast_tanh(float x) {
    float e = __expf(2.0f * x);
    return 1.0f - 2.0f * __builtin_amdgcn_rcpf(e + 1.0f);
}

// ================= pre v3: ALL roles in 256 blocks, one dispatch round ==================
// Every block (sequential phases, all patterns identical to the R3 champion):
//   P0: issue 2 scattered wl gathers (i = bid, bid+256) — latency hidden under P1/P2
//   P1: pack 1 float4 of attn_w -> fp16 (threads 0..255)
//   P2: dec GEMV for (b = bid>>2, qq = bid&3)  [R3 role C verbatim]
//   P3: stage full coverage transposed in cs[512][65] (coalesced; ONE stage feeds TWO i)
//   P4: dual-accumulate MAC: one cs read -> 2 FMAs; shfl-reduce; 2 cov_feat outputs
// LDS 141 KB (cs 133.1 + wl2 4 + sbuf 2 + pr 2) -> 1 block/CU, 256 blocks = 1 round
// (was 896 blocks = 3.5 rounds with coverage staged 512x).
__launch_bounds__(512)
__global__ void pre_kernel(const float* __restrict__ cvg_w, const float* __restrict__ cvg_b,
                           const float* __restrict__ coverage,
                           const float* __restrict__ aw, USH* __restrict__ bh16,
                           const float* __restrict__ hidden, const float* __restrict__ dec_w,
                           const float* __restrict__ dec_b,
                           float* __restrict__ dec_feat, float* __restrict__ cov_feat) {
    __shared__ float wl2[1024];            // w_eff rows for i0, i1
    __shared__ float cs[512 * 65];         // [j][c] coverage transposed, pad 65
    __shared__ float sbuf[512];
    __shared__ float pr[512];
    const int bid = blockIdx.x, t = threadIdx.x;
    const int i0 = bid, i1 = bid + 256;

    // P0: scattered line-gathers (1 line each; consumed after the sync)
    wl2[t]       = cvg_w[((size_t)(i0 * L_ + t)) * H_ + CENTER];
    wl2[512 + t] = cvg_w[((size_t)(i1 * L_ + t)) * H_ + CENTER];

    // P1: attn_w fp32 -> fp16 pack (65536 float4 total / 256 blocks = 256 per block)
    if (t < 256) {
        int i = bid * 256 + t;
        float4 x = *(const float4*)&aw[(size_t)i * 4];
        float xs[4] = {x.x, x.y, x.z, x.w};
        u16x4 h;
        #pragma unroll
        for (int j = 0; j < 4; ++j)
            h[j] = __builtin_bit_cast(USH, (_Float16)xs[j]);
        *(u16x4*)&bh16[(size_t)i * 4] = h;
    }

    // P2a: dec hidden stage
    const int b = bid >> 2, qq = bid & 3;
    const int ol = t & 127, part = t >> 7;
    sbuf[t] = hidden[b * H_ + t];
    __syncthreads();

    // P2b: dec GEMV compute (R3 verbatim)
    {
        const float* row  = dec_w + (size_t)(qq * 128 + ol) * H_ + part * 128;
        const float* hseg = sbuf + part * 128;
        float d0 = 0.f, d1 = 0.f, d2 = 0.f, d3 = 0.f;
        #pragma unroll
        for (int k = 0; k < 128; k += 16) {
            float4 w0 = *(const float4*)&row[k];
            float4 w1 = *(const float4*)&row[k + 4];
            float4 w2 = *(const float4*)&row[k + 8];
            float4 w3 = *(const float4*)&row[k + 12];
            d0 += w0.x * hseg[k]      + w0.y * hseg[k + 1]  + w0.z * hseg[k + 2]  + w0.w * hseg[k + 3];
            d1 += w1.x * hseg[k + 4]  + w1.y * hseg[k + 5]  + w1.z * hseg[k + 6]  + w1.w * hseg[k + 7];
            d2 += w2.x * hseg[k + 8]  + w2.y * hseg[k + 9]  + w2.z * hseg[k + 10] + w2.w * hseg[k + 11];
            d3 += w3.x * hseg[k + 12] + w3.y * hseg[k + 13] + w3.z * hseg[k + 14] + w3.w * hseg[k + 15];
        }
        pr[t] = d0 + d1 + d2 + d3;
    }

    // P3: coverage staging (R3 verbatim — coalesced, write 2/bank)
    #pragma unroll 8
    for (int c = 0; c < 64; ++c)
        cs[t * 65 + c] = coverage[c * L_ + t];
    __syncthreads();

    // P2c: dec output
    if (t < 128)
        dec_feat[b * H_ + qq * 128 + t] = pr[t] + pr[t + 128] + pr[t + 256] + pr[t + 384]
                                          + dec_b[qq * 128 + t];

    // P4: dual MAC (one cs read -> two FMAs), shfl-reduce, two outputs
    {
        const int bb = t >> 3, jg = t & 7;
        float s0 = 0.f, s1 = 0.f;
        #pragma unroll 8
        for (int jj = 0; jj < 64; ++jj) {
            int j = jg * 64 + ((jj + jg * 8) & 63);        // rotation: read 2/bank
            float c = cs[j * 65 + bb];
            s0 += c * wl2[j];
            s1 += c * wl2[512 + j];
        }
        s0 += __shfl_xor(s0, 1, 64);
        s0 += __shfl_xor(s0, 2, 64);
        s0 += __shfl_xor(s0, 4, 64);
        s1 += __shfl_xor(s1, 1, 64);
        s1 += __shfl_xor(s1, 2, 64);
        s1 += __shfl_xor(s1, 4, 64);
        if (jg == 0) {
            cov_feat[bb * L_ + i0] = s0 + cvg_b[i0];
            cov_feat[bb * L_ + i1] = s1 + cvg_b[i1];
        }
    }
}

// ================= fused MFMA GEMM (fp16) + tanh + dot(v) -> partial scores =============
// (byte-identical to R7, the 67.4 us best: BN=256 halves, 2 blocks/CU, 8 waves 2Mx4N,
//  B triple-buffered depth-2, A reg-prefetch depth-2 + LDS dbuf, ONE barrier/step,
//  counted vmcnt(4).)
#define BM 128

#define STAGE_B(BUF, KS1)                                                                  \
    {                                                                                      \
        _Pragma("unroll")                                                                  \
        for (int it = 0; it < 2; ++it)                                                     \
            __builtin_amdgcn_global_load_lds(                                              \
                (const __attribute__((address_space(1))) void*)(bh16 + goffB[it] + (KS1) * 32), \
                (__attribute__((address_space(3))) void*)&Bsh[BUF][(wv * 2 + it) * 512],   \
                16, 0, 0);                                                                 \
    }

#define CVTWRITEA2(BUF, A4a, A4b)                                                          \
    {                                                                                      \
        float axs[8] = {A4a.x, A4a.y, A4a.z, A4a.w, A4b.x, A4b.y, A4b.z, A4b.w};           \
        u16x8 hh;                                                                          \
        _Pragma("unroll")                                                                  \
        for (int j = 0; j < 8; ++j)                                                        \
            hh[j] = __builtin_bit_cast(USH, (_Float16)axs[j]);                             \
        *(u16x8*)&Ash[BUF][awoff] = hh;                                                    \
    }

__launch_bounds__(512, 4)
__global__ void fused_score_mfma(const float* __restrict__ enc,
                                 const USH* __restrict__ bh16,
                                 const float* __restrict__ attn_b,
                                 const float* __restrict__ dec_feat,
                                 const float* __restrict__ cov_feat,
                                 const float* __restrict__ v,
                                 float* __restrict__ spart) {
    __shared__ USH Bsh[3][8192];       // [buf][256n x 32k swizzled fp16] = 48 KB
    __shared__ USH Ash[2][4096];       // [buf][128r x 32k swizzled fp16] = 16 KB

    const int t  = threadIdx.x;
    const int wv = t >> 6, ln = t & 63;
    const int wr = wv >> 2, wc = wv & 3;     // 2M x 4N, wave tile 64 x 64
    const int q  = ln >> 4, cl = ln & 15;
    const int mt = blockIdx.x, half = blockIdx.y;
    const int m0 = mt * BM;
    const int b  = mt >> 2;                  // 4 row-tiles per batch row
    const int n0 = half * 256;

    int goffB[2];
    #pragma unroll
    for (int it = 0; it < 2; ++it) {
        int c   = wv * 2 + it;               // 16 chunks cover 256 n
        int srl = ln >> 3;
        int u   = (ln & 7) ^ (srl & 7);
        int n   = n0 + c * 16 + srl * 2 + (u >> 2);
        goffB[it] = n * 512 + (u & 3) * 8;
    }
    const int sA   = (((cl & 1) * 4 + q) ^ ((cl >> 1) & 7)) * 8;
    const int aoff = wr * 2048 + (cl >> 1) * 64 + sA;
    const int boff = wc * 2048 + (cl >> 1) * 64 + sA;

    const int arow = t >> 2, ak4 = t & 3;    // 512 thr: 8 floats (2 float4) per thread
    const int asw  = ((arow & 1) * 4 + ak4) ^ ((arow >> 1) & 7);
    const int awoff = (arow >> 1) * 64 + asw * 8;
    const float* agsrc = enc + (size_t)(m0 + arow) * H_ + ak4 * 8;

    f32x4 acc[4][4];
    #pragma unroll
    for (int mf = 0; mf < 4; ++mf)
        #pragma unroll
        for (int nf = 0; nf < 4; ++nf) acc[mf][nf] = (f32x4){0.f, 0.f, 0.f, 0.f};

    float4 aPa = *(const float4*)(agsrc + 32);
    float4 aPb = *(const float4*)(agsrc + 36);
    float4 c0a = *(const float4*)agsrc;
    float4 c0b = *(const float4*)(agsrc + 4);
    __builtin_amdgcn_sched_barrier(0);
    STAGE_B(0, 0);
    STAGE_B(1, 1);
    __builtin_amdgcn_sched_barrier(0);
    CVTWRITEA2(0, c0a, c0b);
    asm volatile("s_waitcnt lgkmcnt(0)" ::: "memory");
    asm volatile("s_waitcnt vmcnt(2)" ::: "memory");
    __builtin_amdgcn_sched_barrier(0);
    __builtin_amdgcn_s_barrier();

    #pragma unroll
    for (int ks = 0; ks < 16; ++ks) {
        const int curB = ks % 3;
        const int curA = ks & 1, nxtA = curA ^ 1;
        float4 aNa, aNb;
        if (ks < 14) {
            STAGE_B((ks + 2) % 3, ks + 2);
            aNa = *(const float4*)(agsrc + (ks + 2) * 32);
            aNb = *(const float4*)(agsrc + (ks + 2) * 32 + 4);
            __builtin_amdgcn_sched_barrier(0);
        }

        f16x8 ah[4];
        #pragma unroll
        for (int mf = 0; mf < 4; ++mf)
            ah[mf] = *(const f16x8*)&Ash[curA][aoff + mf * 512];
        __builtin_amdgcn_s_setprio(1);
        #pragma unroll
        for (int nf = 0; nf < 4; ++nf) {
            f16x8 bh = *(const f16x8*)&Bsh[curB][boff + nf * 512];
            #pragma unroll
            for (int mf = 0; mf < 4; ++mf)
                acc[mf][nf] = __builtin_amdgcn_mfma_f32_16x16x32_f16(ah[mf], bh, acc[mf][nf], 0, 0, 0);
        }
        __builtin_amdgcn_s_setprio(0);

        if (ks < 15) {
            CVTWRITEA2(nxtA, aPa, aPb);
            aPa = aNa; aPb = aNb;
            asm volatile("s_waitcnt lgkmcnt(0)" ::: "memory");
            if (ks < 14)
                asm volatile("s_waitcnt vmcnt(4)" ::: "memory");
            else
                asm volatile("s_waitcnt vmcnt(0)" ::: "memory");
            __builtin_amdgcn_sched_barrier(0);
            __builtin_amdgcn_s_barrier();
        }
    }
    __syncthreads();

    float (*scred)[BM] = (float (*)[BM])Ash;
    float addv[4], vvv[4];
    #pragma unroll
    for (int nf = 0; nf < 4; ++nf) {
        int n = n0 + wc * 64 + nf * 16 + cl;
        addv[nf] = attn_b[n] + dec_feat[b * H_ + n];
        vvv[nf]  = v[b * H_ + n];
    }
    #pragma unroll
    for (int mf = 0; mf < 4; ++mf) {
        #pragma unroll
        for (int reg = 0; reg < 4; ++reg) {
            int row = wr * 64 + mf * 16 + q * 4 + reg;
            float cf = cov_feat[m0 + row];
            float s = 0.f;
            #pragma unroll
            for (int nf = 0; nf < 4; ++nf)
                s += fast_tanh(acc[mf][nf][reg] + addv[nf] + cf) * vvv[nf];
            s += __shfl_xor(s, 1, 64);
            s += __shfl_xor(s, 2, 64);
            s += __shfl_xor(s, 4, 64);
            s += __shfl_xor(s, 8, 64);
            if (cl == 0) scred[wc][row] = s;
        }
    }
    __syncthreads();
    if (t < BM) {
        float s = 0.f;
        #pragma unroll
        for (int g = 0; g < 4; ++g) s += scred[g][t];
        spart[half * (B_ * L_) + m0 + t] = s;
    }
}

// ================= smctx: masked softmax + outputs + context ============================
// (byte-identical to R7: 1024 threads, float4 enc loads, scores = spart[0]+spart[1].)
__launch_bounds__(1024)
__global__ void smctx_kernel(const float* __restrict__ spart, const int* __restrict__ mask,
                             const float* __restrict__ coverage, const float* __restrict__ enc,
                             float* __restrict__ out) {
    __shared__ float w[512];
    __shared__ float red[16];
    __shared__ float red2[16];
    __shared__ float4 cred4[32][32];   // 16 KB
    const int bid = blockIdx.x, b = bid >> 2, hc = bid & 3, t = threadIdx.x;
    const int wv = t >> 6, ln = t & 63;

    float sv = 0.f; bool mk = false;
    if (t < 512) {
        mk = (mask[b * L_ + t] == 1);
        sv = spart[b * L_ + t] + spart[B_ * L_ + b * L_ + t];
    }
    float val = (t < 512 && mk) ? sv : -INFINITY;

    float r = val;
    #pragma unroll
    for (int d = 1; d <= 32; d <<= 1) r = fmaxf(r, __shfl_xor(r, d, 64));
    if (ln == 0) red[wv] = r;
    __syncthreads();
    float gmax = red[0];
    #pragma unroll
    for (int i = 1; i < 16; ++i) gmax = fmaxf(gmax, red[i]);

    float p = (t < 512 && mk) ? __expf(sv - gmax) : 0.f;
    float qq = p;
    #pragma unroll
    for (int d = 1; d <= 32; d <<= 1) qq += __shfl_xor(qq, d, 64);
    if (ln == 0) red2[wv] = qq;
    __syncthreads();
    float tot = 0.f;
    #pragma unroll
    for (int i = 0; i < 16; ++i) tot += red2[i];

    float wt = p / tot;
    if (t < 512) {
        w[t] = wt;
        if (hc == 0) {
            out[B_ * H_ + b * L_ + t] = wt;                                   // attn_weights
            out[B_ * H_ + B_ * L_ + b * L_ + t] = coverage[b * L_ + t] + wt;  // new_coverage
        }
    }
    __syncthreads();

    const int c4 = t & 31, rg = t >> 5;    // 32 row-groups x 32 float4 columns
    const float4* ebase = (const float4*)enc
                          + ((size_t)(b * L_ + rg)) * 128 + hc * 32 + c4;
    float4 a4 = {0.f, 0.f, 0.f, 0.f};
    #pragma unroll
    for (int k = 0; k < 16; ++k) {         // rows rg, rg+32, ..., rg+480
        float wl_ = w[rg + 32 * k];
        float4 e = ebase[(size_t)(32 * k) * 128];
        a4.x += wl_ * e.x; a4.y += wl_ * e.y; a4.z += wl_ * e.z; a4.w += wl_ * e.w;
    }
    cred4[rg][c4] = a4;
    __syncthreads();
    if (t < 32) {
        float4 s = {0.f, 0.f, 0.f, 0.f};
        #pragma unroll
        for (int g = 0; g < 32; ++g) {
            float4 c = cred4[g][t];
            s.x += c.x; s.y += c.y; s.z += c.z; s.w += c.w;
        }
        *(float4*)&out[b * H_ + hc * 128 + t * 4] = s;
    }
}

extern "C" void kernel_launch(void* const* d_in, const int* in_sizes, int n_in,
                              void* d_out, int out_size, void* d_ws, size_t ws_size,
                              hipStream_t stream) {
    const float* enc      = (const float*)d_in[0];
    const int*   mask     = (const int*)d_in[1];
    const float* hidden   = (const float*)d_in[2];
    const float* coverage = (const float*)d_in[3];
    const float* attn_w   = (const float*)d_in[4];
    const float* attn_b   = (const float*)d_in[5];
    const float* dec_w    = (const float*)d_in[6];
    const float* dec_b    = (const float*)d_in[7];
    const float* cvg_w    = (const float*)d_in[8];
    const float* cvg_b    = (const float*)d_in[9];
    const float* v        = (const float*)d_in[10];
    float* out = (float*)d_out;
    float* ws  = (float*)d_ws;
    float* dec_feat = ws + 32768;
    float* cov_feat = ws + 65536;
    float* spart    = ws + 98304;
    USH* bpk = (USH*)(ws + 360448);

    hipLaunchKernelGGL(pre_kernel,       dim3(256),     dim3(512),  0, stream,
                       cvg_w, cvg_b, coverage, attn_w, bpk, hidden, dec_w, dec_b,
                       dec_feat, cov_feat);
    hipLaunchKernelGGL(fused_score_mfma, dim3(256, 2),  dim3(512),  0, stream,
                       enc, bpk, attn_b, dec_feat, cov_feat, v, spart);
    hipLaunchKernelGGL(smctx_kernel,     dim3(256),     dim3(1024), 0, stream,
                       spart, mask, coverage, enc, out);
}